// Round 4
// baseline (252.578 us; speedup 1.0000x reference)
//
#include <hip/hip_runtime.h>
#include <cstddef>

// RNN h_t = tanh(x_t W_ih^T + b + h_{t-1} W_hh^T), return h_T. B=4096,T=512,IN=15,H=20.
//
// R1 post-mortem: chain-bound at 483 cyc/step — LDS h write->read round trip
// dominates. R2/R3: h exchange moved to the VALU pipe via DPP row rotations
// (v_fmac_f32 row_ror:r inline asm, src0-dpp), 16 lanes/batch so the rotation
// group == DPP row (rows are 16 lanes -> batches isolated). Lane k owns h_k
// and replicated h_{16+(k&3)} (20 = 16+4; the 4 extras 4x-replicated so
// rotations r=0..3 of reg2 reach all of them). Weights loaded pre-rotated per
// lane; DPP direction probed at runtime (update_dpp) and folded into weight
// LOAD indexing (no dual code path).
// x-projection precomputed per 32-step chunk (f16 dot2, bias folded into
// slot 15 against x_pad==1.0), stored f32 in LDS; the recurrent loop reads 2
// prefetchable ds_read_b32 per step — off the dependency chain.
// R3 fixes vs R2: __fp16 vector types for cvt_pkrtz/fdot2; manual constant-
// index expansion of the shufflevector dot loop.

typedef float g4 __attribute__((ext_vector_type(4), aligned(4)));
typedef float g2 __attribute__((ext_vector_type(2), aligned(4)));
typedef float v4f __attribute__((ext_vector_type(4)));
typedef __fp16 h2t __attribute__((ext_vector_type(2)));
typedef __fp16 v16h __attribute__((ext_vector_type(16)));

#define TT 512
#define IN 15
#define HD 20
#define CH 32
#define NCH (TT / CH)
#define XPS 25               // xp row stride (floats), odd -> spread banks
#define GS (32 * XPS + 8)    // 808; mod 32 == 8 -> group offsets 2-way (free)

// fused DPP fmac: acc += (row_ror:R of h) * w   [src0 carries the DPP]
#define HH(acc, h, w, R)                                                     \
  asm("v_fmac_f32 %0, %1, %2 row_ror:" #R " row_mask:0xf bank_mask:0xf"      \
      : "+v"(acc) : "v"(h), "v"(w))

// one f16x2 pair of the 16-wide W_ih row dotted into both staged x rows
#define FDI(i)                                                               \
  {                                                                          \
    h2t wp = __builtin_shufflevector(wv, wv, 2 * (i), 2 * (i) + 1);          \
    a = __builtin_amdgcn_fdot2(xa[i], wp, a, false);                         \
    c = __builtin_amdgcn_fdot2(xb[i], wp, c, false);                         \
  }

__global__ __launch_bounds__(64, 1) void rnn_dpp(
    const float* __restrict__ feature, const float* __restrict__ W_ih,
    const float* __restrict__ W_hh, const float* __restrict__ b_ih,
    const float* __restrict__ b_hh, float* __restrict__ out) {
  __shared__ float xpL[4 * GS + 40];          // [g][t][j] xp, stride XPS
  __shared__ __fp16 wihL[HD][16];             // W_ih rows f16, slot15 = bias

  const int lane = threadIdx.x;
  const int g = lane >> 4;                    // batch group 0..3
  const int k = lane & 15;                    // lane-in-row
  const int b = blockIdx.x * 4 + g;

  // --- one-time: W_ih (+bias at [15], pairs with x_pad==1.0) into LDS
  if (lane < HD) {
    const float* wr = W_ih + lane * IN;
#pragma unroll
    for (int i = 0; i < IN; ++i) wihL[lane][i] = (__fp16)wr[i];
    wihL[lane][15] = (__fp16)(b_ih[lane] + b_hh[lane]);
  }
  // same-wave LDS: program order suffices, no barrier.

  // --- DPP direction probe: does row_ror:1 deliver lane (k+1)&15 or (k-1)&15?
  const int probe = __builtin_amdgcn_update_dpp(0, k, 0x121, 0xf, 0xf, true);
  const bool plus = (probe == ((k + 1) & 15));

  // --- W_hh rows for my two outputs, loaded in rotation order
  const int j2 = 16 + (k & 3);
  float wA1[16], wB1[16], wA2[4], wB2[4];
#pragma unroll
  for (int r = 0; r < 16; ++r) {
    const int s = (plus ? (k + r) : (k - r)) & 15;
    wA1[r] = W_hh[k * HD + s];
    wB1[r] = W_hh[j2 * HD + s];
  }
#pragma unroll
  for (int r = 0; r < 4; ++r) {
    const int s = 16 + ((plus ? (k + r) : (k - r)) & 3);
    wA2[r] = W_hh[k * HD + s];
    wB2[r] = W_hh[j2 * HD + s];
  }

  // --- x staging: lane stages rows t0+k and t0+16+k of batch b (15 f32 each)
  const float* rb = feature + ((size_t)b * TT) * IN;
  g4 rA0, rA1, rA2; g2 rA3; float rA4;
  g4 rB0, rB1, rB2; g2 rB3; float rB4;
  auto issue = [&](int t0) {
    const float* s = rb + (size_t)(t0 + k) * IN;
    rA0 = *(const g4*)(s);      rA1 = *(const g4*)(s + 4);
    rA2 = *(const g4*)(s + 8);  rA3 = *(const g2*)(s + 12);  rA4 = s[14];
    const float* s2 = rb + (size_t)(t0 + 16 + k) * IN;
    rB0 = *(const g4*)(s2);     rB1 = *(const g4*)(s2 + 4);
    rB2 = *(const g4*)(s2 + 8); rB3 = *(const g2*)(s2 + 12); rB4 = s2[14];
  };

  // --- xp phase: 20 dots of 15 (+bias) per staged row, f16 dot2, store f32
  auto do_xp = [&]() {
    h2t xa[8], xb[8];
    xa[0] = __builtin_amdgcn_cvt_pkrtz(rA0.x, rA0.y);
    xa[1] = __builtin_amdgcn_cvt_pkrtz(rA0.z, rA0.w);
    xa[2] = __builtin_amdgcn_cvt_pkrtz(rA1.x, rA1.y);
    xa[3] = __builtin_amdgcn_cvt_pkrtz(rA1.z, rA1.w);
    xa[4] = __builtin_amdgcn_cvt_pkrtz(rA2.x, rA2.y);
    xa[5] = __builtin_amdgcn_cvt_pkrtz(rA2.z, rA2.w);
    xa[6] = __builtin_amdgcn_cvt_pkrtz(rA3.x, rA3.y);
    xa[7] = __builtin_amdgcn_cvt_pkrtz(rA4, 1.0f);       // pad pairs with bias
    xb[0] = __builtin_amdgcn_cvt_pkrtz(rB0.x, rB0.y);
    xb[1] = __builtin_amdgcn_cvt_pkrtz(rB0.z, rB0.w);
    xb[2] = __builtin_amdgcn_cvt_pkrtz(rB1.x, rB1.y);
    xb[3] = __builtin_amdgcn_cvt_pkrtz(rB1.z, rB1.w);
    xb[4] = __builtin_amdgcn_cvt_pkrtz(rB2.x, rB2.y);
    xb[5] = __builtin_amdgcn_cvt_pkrtz(rB2.z, rB2.w);
    xb[6] = __builtin_amdgcn_cvt_pkrtz(rB3.x, rB3.y);
    xb[7] = __builtin_amdgcn_cvt_pkrtz(rB4, 1.0f);
    float* d1 = xpL + g * GS + k * XPS;          // row t0+k
    float* d2 = xpL + g * GS + (16 + k) * XPS;   // row t0+16+k
#pragma unroll
    for (int j0 = 0; j0 < HD; j0 += 4) {
      v4f bufA, bufB;
#pragma unroll
      for (int jj = 0; jj < 4; ++jj) {
        v16h wv = *(const v16h*)&wihL[j0 + jj][0];   // 2x ds_read_b128 bcast
        float a = 0.f, c = 0.f;
        FDI(0) FDI(1) FDI(2) FDI(3) FDI(4) FDI(5) FDI(6) FDI(7)
        bufA[jj] = a; bufB[jj] = c;
      }
      *(v4f*)(d1 + j0) = bufA;
      *(v4f*)(d2 + j0) = bufB;
    }
  };

  issue(0);
  do_xp();

  float h1 = 0.f, h2v = 0.f;
  const float* xr1 = xpL + g * GS + k;
  const float* xr2 = xpL + g * GS + 16 + (k & 3);

  for (int c = 0; c < NCH; ++c) {
    if (c + 1 < NCH) issue((c + 1) * CH);   // global prefetch (regs held)
    float p1 = xr1[0], p2 = xr2[0];
#pragma unroll 4
    for (int t = 0; t < CH; ++t) {
      float a0 = p1, a1 = 0.f, b0 = p2, b1 = 0.f;
      // prefetch next step's xp (t=31 reads pad garbage; re-read at chunk top)
      p1 = xr1[(t + 1) * XPS];
      p2 = xr2[(t + 1) * XPS];
      // h(0..15) part: rotation r pairs with pre-rotated weight r
      a0 = fmaf(h1, wA1[0], a0);  b0 = fmaf(h1, wB1[0], b0);
      HH(a1, h1, wA1[1], 1);   HH(b1, h1, wB1[1], 1);
      HH(a0, h1, wA1[2], 2);   HH(b0, h1, wB1[2], 2);
      HH(a1, h1, wA1[3], 3);   HH(b1, h1, wB1[3], 3);
      HH(a0, h1, wA1[4], 4);   HH(b0, h1, wB1[4], 4);
      HH(a1, h1, wA1[5], 5);   HH(b1, h1, wB1[5], 5);
      HH(a0, h1, wA1[6], 6);   HH(b0, h1, wB1[6], 6);
      HH(a1, h1, wA1[7], 7);   HH(b1, h1, wB1[7], 7);
      HH(a0, h1, wA1[8], 8);   HH(b0, h1, wB1[8], 8);
      HH(a1, h1, wA1[9], 9);   HH(b1, h1, wB1[9], 9);
      HH(a0, h1, wA1[10], 10); HH(b0, h1, wB1[10], 10);
      HH(a1, h1, wA1[11], 11); HH(b1, h1, wB1[11], 11);
      HH(a0, h1, wA1[12], 12); HH(b0, h1, wB1[12], 12);
      HH(a1, h1, wA1[13], 13); HH(b1, h1, wB1[13], 13);
      HH(a0, h1, wA1[14], 14); HH(b0, h1, wB1[14], 14);
      HH(a1, h1, wA1[15], 15); HH(b1, h1, wB1[15], 15);
      // h(16..19) part: replicated in reg2, rotations 0..3 reach all 4
      a0 = fmaf(h2v, wA2[0], a0); b0 = fmaf(h2v, wB2[0], b0);
      HH(a1, h2v, wA2[1], 1); HH(b1, h2v, wB2[1], 1);
      HH(a0, h2v, wA2[2], 2); HH(b0, h2v, wB2[2], 2);
      HH(a1, h2v, wA2[3], 3); HH(b1, h2v, wB2[3], 3);
      const float s1 = a0 + a1, s2 = b0 + b1;
      // tanh(s) = 1 - 2/(1+e^{2s})
      const float e1 = exp2f(s1 * 2.8853900817779268f);
      const float e2 = exp2f(s2 * 2.8853900817779268f);
      h1  = 1.f - 2.f * __builtin_amdgcn_rcpf(1.f + e1);
      h2v = 1.f - 2.f * __builtin_amdgcn_rcpf(1.f + e2);
    }
    if (c + 1 < NCH) do_xp();   // same-wave LDS: writes ordered after reads
  }

  out[(size_t)b * HD + k] = h1;
  if (k < 4) out[(size_t)b * HD + 16 + k] = h2v;
}

extern "C" void kernel_launch(void* const* d_in, const int* in_sizes, int n_in,
                              void* d_out, int out_size, void* d_ws, size_t ws_size,
                              hipStream_t stream) {
  const float* feature = (const float*)d_in[0];
  const float* W_ih    = (const float*)d_in[1];
  const float* W_hh    = (const float*)d_in[2];
  const float* b_ih    = (const float*)d_in[3];
  const float* b_hh    = (const float*)d_in[4];
  float* out = (float*)d_out;
  const int B = in_sizes[0] / (TT * IN);   // 4096
  rnn_dpp<<<B / 4, 64, 0, stream>>>(feature, W_ih, W_hh, b_ih, b_hh, out);
}